// Round 13
// baseline (2065.572 us; speedup 1.0000x reference)
//
#include <hip/hip_runtime.h>
#include <stdint.h>

#define NN   100000
#define NE   1600000
#define NG   512
#define HID  128
#define NOUT 64
#define BK   512
#define NBUK ((NN + BK - 1) / BK)            // 196 dst-buckets of 512
#define AHIST_E 4096
#define NAH  ((NE + AHIST_E - 1) / AHIST_E)  // 391
#define CHUNK 8192
#define NSC  ((NE + CHUNK - 1) / CHUNK)      // 196
#define N1BLK 32                              // nodes per agg1e block (NN%32==0)
#define NAB1 (NN / N1BLK)                     // 3125
#define EB2  2048
#define NAB2 ((NE + EB2 - 1) / EB2)           // 782
#define GSP  16
#define SPBLK 1024
#define NSPB ((NN + SPBLK - 1) / SPBLK)       // 98

typedef __bf16 bf16_t;
typedef bf16_t bf16x8 __attribute__((ext_vector_type(8)));
typedef float  f32x4  __attribute__((ext_vector_type(4)));
typedef unsigned int u32;
typedef u32 u32x2 __attribute__((ext_vector_type(2)));
typedef u32 u32x4 __attribute__((ext_vector_type(4)));
typedef unsigned short u16;

struct __align__(8) EdgeT { int d, s; };

__device__ __forceinline__ u16 f2b(float f) {
    union { float f; u32 u; } v; v.f = f;
    u32 u = v.u + 0x7fffu + ((v.u >> 16) & 1u);   // RNE
    return (u16)(u >> 16);
}
__device__ __forceinline__ float blo(u32 u) {
    union { u32 u; float f; } v; v.u = u << 16; return v.f;
}
__device__ __forceinline__ float bhi(u32 u) {
    union { u32 u; float f; } v; v.u = u & 0xffff0000u; return v.f;
}

// ---------------- CSR build, bucketed (R6-proven) ----------------
__global__ __launch_bounds__(256) void k_bhist(const int* __restrict__ dst,
                                               int* __restrict__ bcnt) {
    __shared__ int h[NBUK];
    int t = threadIdx.x;
    for (int i = t; i < NBUK; i += 256) h[i] = 0;
    __syncthreads();
    int e0 = blockIdx.x * AHIST_E;
    int e1 = min(NE, e0 + AHIST_E);
    for (int e = e0 + t; e < e1; e += 256) atomicAdd(&h[dst[e] >> 9], 1);
    __syncthreads();
    for (int i = t; i < NBUK; i += 256) if (h[i]) atomicAdd(&bcnt[i], h[i]);
}

__global__ __launch_bounds__(256) void k_bscan(const int* __restrict__ bcnt,
                                               int* __restrict__ boff, int* __restrict__ gcur,
                                               int* __restrict__ rpN) {
    __shared__ int sh[256];
    int t = threadIdx.x;
    int v = (t < NBUK) ? bcnt[t] : 0;
    sh[t] = v; __syncthreads();
    for (int off = 1; off < 256; off <<= 1) {
        int x = (t >= off) ? sh[t - off] : 0;
        __syncthreads();
        sh[t] += x;
        __syncthreads();
    }
    if (t < NBUK) { int b = sh[t] - v; boff[t] = b; gcur[t] = b; }
    if (t == 0) { boff[NBUK] = NE; rpN[0] = NE; }
}

__global__ __launch_bounds__(256) void k_scatter(const int* __restrict__ src,
                                                 const int* __restrict__ dst,
                                                 int* __restrict__ gcur,
                                                 EdgeT* __restrict__ ebuf) {
    __shared__ int hist[NBUK], base[NBUK];
    int t = threadIdx.x;
    for (int i = t; i < NBUK; i += 256) hist[i] = 0;
    __syncthreads();
    int e0 = blockIdx.x * CHUNK;
    int e1 = min(NE, e0 + CHUNK);
    for (int e = e0 + t; e < e1; e += 256) atomicAdd(&hist[dst[e] >> 9], 1);
    __syncthreads();
    for (int i = t; i < NBUK; i += 256) {
        int h = hist[i];
        base[i] = h ? atomicAdd(&gcur[i], h) : 0;
        hist[i] = 0;
    }
    __syncthreads();
    for (int e = e0 + t; e < e1; e += 256) {
        int d = dst[e], bk = d >> 9;
        int r = atomicAdd(&hist[bk], 1);
        EdgeT p; p.d = d; p.s = src[e];
        ebuf[base[bk] + r] = p;
    }
}

__global__ __launch_bounds__(256) void k_bucketc(const EdgeT* __restrict__ ebuf,
                                                 const int* __restrict__ boff,
                                                 const int* __restrict__ batch,
                                                 int* __restrict__ rp, float* __restrict__ dinv,
                                                 int* __restrict__ cntg, int* __restrict__ col,
                                                 int* __restrict__ dcol) {
    __shared__ int cnt[BK], pos[BK], run[BK], s2[256];
    int b = blockIdx.x, t = threadIdx.x;
    int d0 = b * BK;
    int e0 = boff[b], e1 = boff[b + 1];
    for (int i = t; i < BK; i += 256) { cnt[i] = 0; run[i] = 0; }
    __syncthreads();
    for (int e = e0 + t; e < e1; e += 256) atomicAdd(&cnt[ebuf[e].d - d0], 1);
    __syncthreads();
    for (int i = t; i < BK; i += 256) {
        int v = d0 + i;
        if (v < NN) {
            dinv[v] = rsqrtf((float)(cnt[i] + 1));
            atomicAdd(&cntg[batch[v]], 1);
        }
    }
    int c0 = cnt[2 * t], c1 = cnt[2 * t + 1];
    int s = c0 + c1; s2[t] = s; __syncthreads();
    for (int off = 1; off < 256; off <<= 1) {
        int x = (t >= off) ? s2[t - off] : 0;
        __syncthreads();
        s2[t] += x;
        __syncthreads();
    }
    int bse = s2[t] - s;
    pos[2 * t] = bse; pos[2 * t + 1] = bse + c0;
    __syncthreads();
    for (int i = t; i < BK; i += 256) {
        int v = d0 + i;
        if (v < NN) rp[v] = e0 + pos[i];
    }
    for (int e = e0 + t; e < e1; e += 256) {
        EdgeT p = ebuf[e];
        int i = p.d - d0;
        int r = atomicAdd(&run[i], 1);
        int slot = e0 + pos[i] + r;
        col[slot]  = p.s;
        dcol[slot] = p.d;
    }
}

// ---------------- fused weight prep (R11-proven) ----------------
__global__ void k_wprep(const float* __restrict__ W1, u16* __restrict__ Wp,
                        const float* __restrict__ W2, const float* __restrict__ Wfc,
                        const float* __restrict__ b2, const float* __restrict__ bfc,
                        u16* __restrict__ Wcp, float* __restrict__ bc) {
    int tid = blockIdx.x * blockDim.x + threadIdx.x;
    if (tid < 2048) {
        int f = tid >> 6, l = tid & 63;
        int c = f >> 2, s = f & 3;
        int n  = (l & 15) * 8 + c;
        int k0 = s * 32 + ((l >> 4) << 3);
#pragma unroll
        for (int j = 0; j < 8; j++) Wp[tid * 8 + j] = f2b(W1[(k0 + j) * HID + n]);
    } else if (tid < 2048 + HID * NOUT) {
        int t2 = tid - 2048;
        int k = t2 >> 6, n = t2 & 63;
        float a = 0.f;
        for (int m = 0; m < HID; m++) a += W2[k * HID + m] * Wfc[m * NOUT + n];
        int s = k >> 5, lh = (k >> 3) & 3, j = k & 7;
        int c = n & 3, l15 = n >> 2;
        int l = (lh << 4) | l15, f = c * 4 + s;
        Wcp[((f * 64 + l) << 3) + j] = f2b(a);
    } else if (tid < 2048 + HID * NOUT + NOUT) {
        int o = tid - 2048 - HID * NOUT;
        float a = bfc[o];
        for (int k = 0; k < HID; k++) a += b2[k] * Wfc[k * NOUT + o];
        bc[o] = a;
    }
}

// ---------------- GEMM1: g = bf16((X @ W1) * dinv[row]), [NN][128] ----------------
__global__ __launch_bounds__(256) void k_gemm(const float* __restrict__ Xf,
                                              const u16* __restrict__ Wp,
                                              const float* __restrict__ dinv,
                                              u16* __restrict__ Gout) {
    int w = threadIdx.x >> 6, l = threadIdx.x & 63;
    int r0  = blockIdx.x * 64 + w * 16;
    int l15 = l & 15, lh = l >> 4;
    int arow = r0 + l15;
    int arc  = (arow < NN) ? arow : (NN - 1);

    f32x4 acc[8];
#pragma unroll
    for (int c = 0; c < 8; c++) acc[c] = (f32x4){0.f, 0.f, 0.f, 0.f};

#pragma unroll
    for (int s = 0; s < 4; s++) {
        int k0 = s * 32 + lh * 8;
        f32x4 p0 = *(const f32x4*)(Xf + (size_t)arc * HID + k0);
        f32x4 p1 = *(const f32x4*)(Xf + (size_t)arc * HID + k0 + 4);
        union { bf16x8 v; u16 h[8]; } au;
#pragma unroll
        for (int j = 0; j < 4; j++) { au.h[j] = f2b(p0[j]); au.h[j + 4] = f2b(p1[j]); }
        bf16x8 a = au.v;
#pragma unroll
        for (int c = 0; c < 8; c++) {
            bf16x8 b = *(const bf16x8*)(Wp + ((c * 4 + s) * 64 + l) * 8);
            acc[c] = __builtin_amdgcn_mfma_f32_16x16x32_bf16(a, b, acc[c], 0, 0, 0);
        }
    }
#pragma unroll
    for (int q = 0; q < 4; q++) {
        int row = r0 + lh * 4 + q;
        if (row < NN) {
            float dv = dinv[row];
            union { u32x4 v; u16 h[8]; } pk;
#pragma unroll
            for (int c = 0; c < 8; c++) pk.h[c] = f2b(acc[c][q] * dv);
            *(u32x4*)(Gout + (size_t)row * HID + l15 * 8) = pk.v;
        }
    }
}

// ---------------- agg1e: edge-centric, 32-node blocks, LDS node table ----------
// Wave gathers 32 consecutive CSR edges per chunk: 16 unmasked u32x2 loads,
// each covering TWO 256B g-rows (lanes 0-31 edge 2k, 32-63 edge 2k+1) ->
// 64 granules in flight.  Segmented-sum into LDS tbl[32][128]; flush applies
// self-loop + dinv^2*relu+bias and writes T rows coalesced.
__global__ __launch_bounds__(256) void k_agg1e(const u16* __restrict__ g,
                                               const int* __restrict__ rp,
                                               const int* __restrict__ col,
                                               const int* __restrict__ dcol,
                                               const float* __restrict__ dinv,
                                               const float* __restrict__ bias,
                                               u16* __restrict__ T) {
    __shared__ float tbl[N1BLK * HID];   // 16 KB
    int b = blockIdx.x, tid = threadIdx.x, w = tid >> 6, l = tid & 63;
    int half = l >> 5, lf = l & 31;
    int n0 = b * N1BLK;
    int e0 = rp[n0], e1 = rp[n0 + N1BLK];
    for (int i = tid; i < N1BLK * HID; i += 256) tbl[i] = 0.f;
    __syncthreads();
    const u16* gl = g + 4 * lf;          // lane's 8B within any 256B row

    for (int ce = e0 + w * 32; ce < e1; ce += 128) {
        int n = e1 - ce; if (n > 32) n = 32;
        int li = (l < n) ? l : (n - 1);
        int s_ = 0, d_ = 0;
        if (l < 32) { s_ = col[ce + li]; d_ = dcol[ce + li]; }
        if (n == 32) {
            u32x2 uu[16];
#pragma unroll
            for (int k = 0; k < 16; k++) {
                int s = __shfl(s_, 2 * k + half);
                uu[k] = *(const u32x2*)(gl + (size_t)s * HID);
            }
#pragma unroll
            for (int k = 0; k < 16; k++) {
                int o = __shfl(d_, 2 * k + half) - n0;
                float* tb = &tbl[o * HID + 4 * lf];
                atomicAdd(tb + 0, blo(uu[k].x));
                atomicAdd(tb + 1, bhi(uu[k].x));
                atomicAdd(tb + 2, blo(uu[k].y));
                atomicAdd(tb + 3, bhi(uu[k].y));
            }
        } else {
            for (int j = 0; j < n; j += 8) {
                u32x2 uu[4]; float mks[4]; int os[4];
#pragma unroll
                for (int k = 0; k < 4; k++) {
                    int k2 = j + 2 * k + half;
                    int ok = (k2 < n);
                    int sl = ok ? k2 : 0;
                    int s = __shfl(s_, sl);
                    os[k] = __shfl(d_, sl) - n0;
                    mks[k] = ok ? 1.f : 0.f;
                    uu[k] = *(const u32x2*)(gl + (size_t)s * HID);
                }
#pragma unroll
                for (int k = 0; k < 4; k++) {
                    float* tb = &tbl[os[k] * HID + 4 * lf];
                    atomicAdd(tb + 0, mks[k] * blo(uu[k].x));
                    atomicAdd(tb + 1, mks[k] * bhi(uu[k].x));
                    atomicAdd(tb + 2, mks[k] * blo(uu[k].y));
                    atomicAdd(tb + 3, mks[k] * bhi(uu[k].y));
                }
            }
        }
    }
    __syncthreads();
    for (int i = tid; i < N1BLK * HID; i += 256) {
        int node = i >> 7, f = i & 127;
        int v = n0 + node;
        float sum = tbl[i] + blo((u32)g[(size_t)v * HID + f]);   // + self loop
        float dv = dinv[v];
        float o = fmaxf(sum * dv + bias[f], 0.f) * dv;           // pre-scaled for L2
        T[(size_t)v * HID + f] = f2b(o);
    }
}

// ---------------- GEMM2: U = bf16(T @ Wc), [NN][64] (128B rows) ----------------
__global__ __launch_bounds__(256) void k_gemm2(const u16* __restrict__ T,
                                               const u16* __restrict__ Wcp,
                                               u16* __restrict__ U) {
    int w = threadIdx.x >> 6, l = threadIdx.x & 63;
    int r0  = blockIdx.x * 64 + w * 16;
    int l15 = l & 15, lh = l >> 4;
    int arow = r0 + l15;
    int arc  = (arow < NN) ? arow : (NN - 1);

    f32x4 acc[4];
#pragma unroll
    for (int c = 0; c < 4; c++) acc[c] = (f32x4){0.f, 0.f, 0.f, 0.f};

#pragma unroll
    for (int s = 0; s < 4; s++) {
        int k0 = s * 32 + lh * 8;
        bf16x8 a = *(const bf16x8*)(T + (size_t)arc * HID + k0);
#pragma unroll
        for (int c = 0; c < 4; c++) {
            bf16x8 b = *(const bf16x8*)(Wcp + ((c * 4 + s) * 64 + l) * 8);
            acc[c] = __builtin_amdgcn_mfma_f32_16x16x32_bf16(a, b, acc[c], 0, 0, 0);
        }
    }
#pragma unroll
    for (int q = 0; q < 4; q++) {
        int row = r0 + lh * 4 + q;
        if (row < NN) {
            union { u32x2 v; u16 h[4]; } pk;
#pragma unroll
            for (int c = 0; c < 4; c++) pk.h[c] = f2b(acc[c][q]);
            *(u32x2*)(U + (size_t)row * NOUT + l15 * 4) = pk.v;
        }
    }
}

// ---------------- agg2e: edge-centric pooled gather of U ----------------
// Block = 2048 consecutive CSR edges (dst-sorted => few graphs).  Wave chunk =
// 32 edges, 16 unmasked u32 pair-loads (2x128B rows/instr).  dinv/batch per
// edge pre-gathered (quasi-sequential).  Accumulate into LDS graph table.
__global__ __launch_bounds__(256) void k_agg2e(const u16* __restrict__ U,
                                               const int* __restrict__ col,
                                               const int* __restrict__ dcol,
                                               const float* __restrict__ dinv,
                                               const int* __restrict__ batch,
                                               float* __restrict__ psum) {
    __shared__ float tbl[GSP * NOUT];    // 4 KB
    __shared__ int sg[2];
    int b = blockIdx.x, tid = threadIdx.x, w = tid >> 6, l = tid & 63;
    int half = l >> 5, lf = l & 31;
    int e0 = b * EB2, e1 = min(NE, e0 + EB2);
    for (int i = tid; i < GSP * NOUT; i += 256) tbl[i] = 0.f;
    if (tid == 0) {
        int gmin = batch[dcol[e0]];
        sg[0] = gmin;
        sg[1] = batch[dcol[e1 - 1]] - gmin + 1;
    }
    __syncthreads();
    int gmin = sg[0];
    const u16* Ul = U + 2 * lf;

    for (int ce = e0 + w * 32; ce < e1; ce += 128) {
        int n = e1 - ce; if (n > 32) n = 32;
        int li = (l < n) ? l : (n - 1);
        int s_ = 0; float dv_ = 0.f; int bg_ = 0;
        if (l < 32) {
            s_ = col[ce + li];
            int d = dcol[ce + li];
            dv_ = dinv[d];
            bg_ = batch[d] - gmin;
        }
        if (n == 32) {
            u32 uu[16];
#pragma unroll
            for (int k = 0; k < 16; k++) {
                int s = __shfl(s_, 2 * k + half);
                uu[k] = *(const u32*)(Ul + (size_t)s * NOUT);
            }
#pragma unroll
            for (int k = 0; k < 16; k++) {
                int sl = 2 * k + half;
                float dv = __shfl(dv_, sl);
                int o = __shfl(bg_, sl);
                float v0 = dv * blo(uu[k]), v1 = dv * bhi(uu[k]);
                if (o < GSP) {
                    atomicAdd(&tbl[o * NOUT + 2 * lf],     v0);
                    atomicAdd(&tbl[o * NOUT + 2 * lf + 1], v1);
                } else {
                    atomicAdd(&psum[(size_t)(gmin + o) * NOUT + 2 * lf],     v0);
                    atomicAdd(&psum[(size_t)(gmin + o) * NOUT + 2 * lf + 1], v1);
                }
            }
        } else {
            for (int j = 0; j < n; j += 8) {
                u32 uu[4]; float dvs[4]; int os[4];
#pragma unroll
                for (int k = 0; k < 4; k++) {
                    int k2 = j + 2 * k + half;
                    int ok = (k2 < n);
                    int sl = ok ? k2 : 0;
                    int s = __shfl(s_, sl);
                    dvs[k] = ok ? __shfl(dv_, sl) : 0.f;
                    os[k]  = __shfl(bg_, sl);
                    uu[k] = *(const u32*)(Ul + (size_t)s * NOUT);
                }
#pragma unroll
                for (int k = 0; k < 4; k++) {
                    float v0 = dvs[k] * blo(uu[k]), v1 = dvs[k] * bhi(uu[k]);
                    if (os[k] < GSP) {
                        atomicAdd(&tbl[os[k] * NOUT + 2 * lf],     v0);
                        atomicAdd(&tbl[os[k] * NOUT + 2 * lf + 1], v1);
                    } else {
                        atomicAdd(&psum[(size_t)(gmin + os[k]) * NOUT + 2 * lf],     v0);
                        atomicAdd(&psum[(size_t)(gmin + os[k]) * NOUT + 2 * lf + 1], v1);
                    }
                }
            }
        }
    }
    __syncthreads();
    int span = sg[1]; if (span > GSP) span = GSP;
    for (int i = tid; i < span * NOUT; i += 256)
        atomicAdd(&psum[(size_t)gmin * NOUT + i], tbl[i]);
}

// ---------------- self-loop pooling: psum[batch[v]] += dinv[v]*U[v] ------------
__global__ __launch_bounds__(256) void k_selfpool2(const u16* __restrict__ U,
                                                   const int* __restrict__ batch,
                                                   const float* __restrict__ dinv,
                                                   float* __restrict__ psum) {
    __shared__ float tbl[GSP * NOUT];
    __shared__ int sg[2];
    int b = blockIdx.x, tid = threadIdx.x, w = tid >> 6, l = tid & 63;
    int half = l >> 5, lf = l & 31;
    int n0 = b * SPBLK, n1 = min(NN, n0 + SPBLK);
    for (int i = tid; i < GSP * NOUT; i += 256) tbl[i] = 0.f;
    if (tid == 0) { sg[0] = batch[n0]; sg[1] = batch[n1 - 1] - batch[n0] + 1; }
    __syncthreads();
    int gmin = sg[0];
    for (int v = n0 + w * 2 + half; v < n1; v += 8) {
        float dv = dinv[v];
        int o = batch[v] - gmin;
        u32 u = *(const u32*)(U + (size_t)v * NOUT + 2 * lf);
        float v0 = dv * blo(u), v1 = dv * bhi(u);
        if (o < GSP) {
            atomicAdd(&tbl[o * NOUT + 2 * lf],     v0);
            atomicAdd(&tbl[o * NOUT + 2 * lf + 1], v1);
        } else {
            atomicAdd(&psum[(size_t)(gmin + o) * NOUT + 2 * lf],     v0);
            atomicAdd(&psum[(size_t)(gmin + o) * NOUT + 2 * lf + 1], v1);
        }
    }
    __syncthreads();
    int span = sg[1]; if (span > GSP) span = GSP;
    for (int i = tid; i < span * NOUT; i += 256)
        atomicAdd(&psum[(size_t)gmin * NOUT + i], tbl[i]);
}

// ---------------- final: out[g][o] = psum[g][o]/cnt + bc[o] ----------------
__global__ __launch_bounds__(256) void k_fc(const float* __restrict__ psum,
                                            const int* __restrict__ cntg,
                                            const float* __restrict__ bc,
                                            float* __restrict__ out) {
    int tid = blockIdx.x * blockDim.x + threadIdx.x;
    if (tid < NG * NOUT) {
        int gph = tid >> 6, o = tid & 63;
        float inv = 1.f / fmaxf((float)cntg[gph], 1.f);
        out[tid] = psum[tid] * inv + bc[o];
    }
}

extern "C" void kernel_launch(void* const* d_in, const int* in_sizes, int n_in,
                              void* d_out, int out_size, void* d_ws, size_t ws_size,
                              hipStream_t stream) {
    const float* x     = (const float*)d_in[0];
    const int*   ei    = (const int*)d_in[1];
    const int*   batch = (const int*)d_in[3];
    const float* W1    = (const float*)d_in[4];
    const float* b1    = (const float*)d_in[5];
    const float* W2    = (const float*)d_in[6];
    const float* b2    = (const float*)d_in[7];
    const float* Wfc   = (const float*)d_in[8];
    const float* bfc   = (const float*)d_in[9];
    float* out = (float*)d_out;

    const int* src = ei;
    const int* dst = ei + NE;

    char* p = (char*)d_ws;
    auto take = [&](size_t bytes) { char* r = p; p += (bytes + 255) & ~(size_t)255; return r; };
    // zero-group (one memset covers bcnt..psum)
    int*   bcnt = (int*)take((size_t)NBUK * 4);
    int*   cntg = (int*)take((size_t)NG * 4);
    float* psum = (float*)take((size_t)NG * NOUT * 4);
    size_t zspan = (size_t)((char*)psum + (size_t)NG * NOUT * 4 - (char*)bcnt);
    int*   boff = (int*)take((size_t)(NBUK + 1) * 4);
    int*   gcur = (int*)take((size_t)NBUK * 4);
    int*   rp   = (int*)take((size_t)(NN + 1) * 4);
    float* dinv = (float*)take((size_t)NN * 4);
    u16*   Wp1  = (u16*)take((size_t)32 * 64 * 8 * 2);
    u16*   Wcp  = (u16*)take((size_t)16 * 64 * 8 * 2);
    float* bc   = (float*)take((size_t)NOUT * 4);
    int*   col  = (int*)take((size_t)NE * 4);
    int*   dcol = (int*)take((size_t)NE * 4);
    u16*   g    = (u16*)take((size_t)NN * HID * 2);
    u16*   t    = (u16*)take((size_t)NN * HID * 2);
    u16*   U    = (u16*)take((size_t)NN * NOUT * 2);
    EdgeT* ebuf = (EdgeT*)g;   // aliased: ebuf consumed by k_bucketc before k_gemm writes g

    hipMemsetAsync(bcnt, 0, zspan, stream);

    k_bhist   <<<NAH, 256, 0, stream>>>(dst, bcnt);
    k_bscan   <<<1, 256, 0, stream>>>(bcnt, boff, gcur, rp + NN);
    k_scatter <<<NSC, 256, 0, stream>>>(src, dst, gcur, ebuf);
    k_bucketc <<<NBUK, 256, 0, stream>>>(ebuf, boff, batch, rp, dinv, cntg, col, dcol);
    k_wprep   <<<(2048 + HID * NOUT + NOUT + 255) / 256, 256, 0, stream>>>
              (W1, Wp1, W2, Wfc, b2, bfc, Wcp, bc);

    k_gemm    <<<(NN + 63) / 64, 256, 0, stream>>>(x, Wp1, dinv, g);
    k_agg1e   <<<NAB1, 256, 0, stream>>>(g, rp, col, dcol, dinv, b1, t);
    k_gemm2   <<<(NN + 63) / 64, 256, 0, stream>>>(t, Wcp, U);
    k_agg2e   <<<NAB2, 256, 0, stream>>>(U, col, dcol, dinv, batch, psum);
    k_selfpool2<<<NSPB, 256, 0, stream>>>(U, batch, dinv, psum);
    k_fc      <<<(NG * NOUT + 255) / 256, 256, 0, stream>>>(psum, cntg, bc, out);
}

// Round 14
// 341.349 us; speedup vs baseline: 6.0512x; 6.0512x over previous
//
#include <hip/hip_runtime.h>
#include <stdint.h>

#define NN   100000
#define NE   1600000
#define NG   512
#define HID  128
#define NOUT 64
#define BK   512
#define NBUK ((NN + BK - 1) / BK)      // 196 buckets of 512 nodes
#define AHIST_E 4096
#define NAH  ((NE + AHIST_E - 1) / AHIST_E)   // 391
#define CHUNK 8192
#define NSC  ((NE + CHUNK - 1) / CHUNK)       // 196

typedef __bf16 bf16_t;
typedef bf16_t bf16x8 __attribute__((ext_vector_type(8)));
typedef float  f32x4  __attribute__((ext_vector_type(4)));
typedef unsigned int u32;
typedef u32 u32x4 __attribute__((ext_vector_type(4)));
typedef unsigned short u16;

struct __align__(8) EdgeT { int d, s; };

__device__ __forceinline__ u16 f2b(float f) {
    union { float f; u32 u; } v; v.f = f;
    u32 u = v.u + 0x7fffu + ((v.u >> 16) & 1u);   // RNE
    return (u16)(u >> 16);
}
__device__ __forceinline__ float blo(u32 u) {
    union { u32 u; float f; } v; v.u = u << 16; return v.f;
}
__device__ __forceinline__ float bhi(u32 u) {
    union { u32 u; float f; } v; v.u = u & 0xffff0000u; return v.f;
}

// ---------------- CSR build, bucketed ----------------
__global__ __launch_bounds__(256) void k_bhist(const int* __restrict__ dst,
                                               int* __restrict__ bcnt) {
    __shared__ int h[NBUK];
    int t = threadIdx.x;
    for (int i = t; i < NBUK; i += 256) h[i] = 0;
    __syncthreads();
    int e0 = blockIdx.x * AHIST_E;
    int e1 = min(NE, e0 + AHIST_E);
    for (int e = e0 + t; e < e1; e += 256) atomicAdd(&h[dst[e] >> 9], 1);
    __syncthreads();
    for (int i = t; i < NBUK; i += 256) if (h[i]) atomicAdd(&bcnt[i], h[i]);
}

__global__ __launch_bounds__(256) void k_bscan(const int* __restrict__ bcnt,
                                               int* __restrict__ boff, int* __restrict__ gcur,
                                               int* __restrict__ rp) {
    __shared__ int sh[256];
    int t = threadIdx.x;
    int v = (t < NBUK) ? bcnt[t] : 0;
    sh[t] = v; __syncthreads();
    for (int off = 1; off < 256; off <<= 1) {
        int x = (t >= off) ? sh[t - off] : 0;
        __syncthreads();
        sh[t] += x;
        __syncthreads();
    }
    if (t < NBUK) { int b = sh[t] - v; boff[t] = b; gcur[t] = b; }
    if (t == 0) { boff[NBUK] = NE; rp[NN] = NE; }
}

__global__ __launch_bounds__(256) void k_scatter(const int* __restrict__ src,
                                                 const int* __restrict__ dst,
                                                 int* __restrict__ gcur,
                                                 EdgeT* __restrict__ ebuf) {
    __shared__ int hist[NBUK], base[NBUK];
    int t = threadIdx.x;
    for (int i = t; i < NBUK; i += 256) hist[i] = 0;
    __syncthreads();
    int e0 = blockIdx.x * CHUNK;
    int e1 = min(NE, e0 + CHUNK);
    for (int e = e0 + t; e < e1; e += 256) atomicAdd(&hist[dst[e] >> 9], 1);
    __syncthreads();
    for (int i = t; i < NBUK; i += 256) {
        int h = hist[i];
        base[i] = h ? atomicAdd(&gcur[i], h) : 0;
        hist[i] = 0;
    }
    __syncthreads();
    for (int e = e0 + t; e < e1; e += 256) {
        int d = dst[e], bk = d >> 9;
        int r = atomicAdd(&hist[bk], 1);
        EdgeT p; p.d = d; p.s = src[e];
        ebuf[base[bk] + r] = p;
    }
}

__global__ __launch_bounds__(256) void k_bucketc(const EdgeT* __restrict__ ebuf,
                                                 const int* __restrict__ boff,
                                                 const int* __restrict__ batch,
                                                 int* __restrict__ rp, float* __restrict__ dinv,
                                                 int* __restrict__ cntg, int* __restrict__ col) {
    __shared__ int cnt[BK], pos[BK], run[BK], s2[256];
    int b = blockIdx.x, t = threadIdx.x;
    int d0 = b * BK;
    int e0 = boff[b], e1 = boff[b + 1];
    for (int i = t; i < BK; i += 256) { cnt[i] = 0; run[i] = 0; }
    __syncthreads();
    for (int e = e0 + t; e < e1; e += 256) atomicAdd(&cnt[ebuf[e].d - d0], 1);
    __syncthreads();
    for (int i = t; i < BK; i += 256) {
        int v = d0 + i;
        if (v < NN) {
            dinv[v] = rsqrtf((float)(cnt[i] + 1));
            atomicAdd(&cntg[batch[v]], 1);
        }
    }
    int c0 = cnt[2 * t], c1 = cnt[2 * t + 1];
    int s = c0 + c1; s2[t] = s; __syncthreads();
    for (int off = 1; off < 256; off <<= 1) {
        int x = (t >= off) ? s2[t - off] : 0;
        __syncthreads();
        s2[t] += x;
        __syncthreads();
    }
    int bse = s2[t] - s;
    pos[2 * t] = bse; pos[2 * t + 1] = bse + c0;
    __syncthreads();
    for (int i = t; i < BK; i += 256) {
        int v = d0 + i;
        if (v < NN) rp[v] = e0 + pos[i];
    }
    for (int e = e0 + t; e < e1; e += 256) {
        EdgeT p = ebuf[e];
        int i = p.d - d0;
        int r = atomicAdd(&run[i], 1);
        col[e0 + pos[i] + r] = p.s;
    }
}

// ---------------- weight pack (fragment order, contiguous-output permutation) ----
__global__ void k_pack(const float* __restrict__ W, u16* __restrict__ Wp) {
    int tid = blockIdx.x * blockDim.x + threadIdx.x;
    if (tid >= 32 * 64) return;
    int f = tid >> 6, l = tid & 63;
    int c = f >> 2, s = f & 3;
    int n  = (l & 15) * 8 + c;
    int k0 = s * 32 + ((l >> 4) << 3);
#pragma unroll
    for (int j = 0; j < 8; j++) Wp[tid * 8 + j] = f2b(W[(k0 + j) * HID + n]);
}

// Wc = W2 @ Wfc [HID x NOUT], bc = b2 @ Wfc + bfc [NOUT]
__global__ void k_wc(const float* __restrict__ W2, const float* __restrict__ Wfc,
                     const float* __restrict__ b2, const float* __restrict__ bfc,
                     float* __restrict__ Wc, float* __restrict__ bc) {
    int tid = blockIdx.x * blockDim.x + threadIdx.x;
    if (tid < HID * NOUT) {
        int i = tid >> 6, o = tid & 63;
        float a = 0.f;
        for (int k = 0; k < HID; k++) a += W2[i * HID + k] * Wfc[k * NOUT + o];
        Wc[i * NOUT + o] = a;
    }
    if (tid < NOUT) {
        float a = bfc[tid];
        for (int k = 0; k < HID; k++) a += b2[k] * Wfc[k * NOUT + tid];
        bc[tid] = a;
    }
}

// ---------------- GEMM: g = bf16((X @ W1) * dinv[row]), dwordx4 stores ----------
__global__ __launch_bounds__(256) void k_gemm(const float* __restrict__ Xf,
                                              const u16* __restrict__ Wp,
                                              const float* __restrict__ dinv,
                                              u16* __restrict__ Gout) {
    int w = threadIdx.x >> 6, l = threadIdx.x & 63;
    int r0  = blockIdx.x * 64 + w * 16;
    int l15 = l & 15, lh = l >> 4;
    int arow = r0 + l15;
    int arc  = (arow < NN) ? arow : (NN - 1);

    f32x4 acc[8];
#pragma unroll
    for (int c = 0; c < 8; c++) acc[c] = (f32x4){0.f, 0.f, 0.f, 0.f};

#pragma unroll
    for (int s = 0; s < 4; s++) {
        int k0 = s * 32 + lh * 8;
        f32x4 p0 = *(const f32x4*)(Xf + (size_t)arc * HID + k0);
        f32x4 p1 = *(const f32x4*)(Xf + (size_t)arc * HID + k0 + 4);
        union { bf16x8 v; u16 h[8]; } au;
#pragma unroll
        for (int j = 0; j < 4; j++) { au.h[j] = f2b(p0[j]); au.h[j + 4] = f2b(p1[j]); }
        bf16x8 a = au.v;
#pragma unroll
        for (int c = 0; c < 8; c++) {
            bf16x8 b = *(const bf16x8*)(Wp + ((c * 4 + s) * 64 + l) * 8);
            acc[c] = __builtin_amdgcn_mfma_f32_16x16x32_bf16(a, b, acc[c], 0, 0, 0);
        }
    }
#pragma unroll
    for (int q = 0; q < 4; q++) {
        int row = r0 + lh * 4 + q;
        if (row < NN) {
            float dv = dinv[row];
            union { u32x4 v; u16 h[8]; } pk;
#pragma unroll
            for (int c = 0; c < 8; c++) pk.h[c] = f2b(acc[c][q] * dv);
            *(u32x4*)(Gout + (size_t)row * HID + l15 * 8) = pk.v;
        }
    }
}

// ---------------- aggregation: one wave per node, lane owns 2 features ----------
// One u32 load per lane per row (64 lanes x 4B = full 256B row, coalesced).
// 16 independent rows in flight; full-line packed store via shfl.
// LAYER 1: T[v] = bf16(dinv[v] * relu(dinv[v]*Sum + b1))   (pre-scaled for layer 2)
// LAYER 2: psum[batch[v]] += dinv[v] * Sum                 (W2/b2 folded into FC)
template<int LAYER>
__global__ __launch_bounds__(256) void k_agg(const u16* __restrict__ g,
                                             const int* __restrict__ rp,
                                             const int* __restrict__ col,
                                             const float* __restrict__ dinv,
                                             const float* __restrict__ bias,
                                             u16* __restrict__ tout,
                                             const int* __restrict__ batch,
                                             float* __restrict__ psum) {
    int w = threadIdx.x >> 6, l = threadIdx.x & 63;
    int v = blockIdx.x * 4 + w;
    if (v >= NN) return;
    int f0 = 2 * l;
    const u16* gl = g + f0;   // this lane's 4B column within any row

    u32 u = *(const u32*)(gl + (size_t)v * HID);   // self loop
    float a0 = blo(u), a1 = bhi(u);

    int e = rp[v], end = rp[v + 1];
    while (e < end) {
        int m = end - e; if (m > 64) m = 64;
        int ci = col[e + ((l < m) ? l : 0)];
        int j = 0;
        for (; j + 16 <= m; j += 16) {
            u32 uu[16];
#pragma unroll
            for (int k = 0; k < 16; k++) {
                int idx = __shfl(ci, j + k);
                uu[k] = *(const u32*)(gl + (size_t)idx * HID);
            }
#pragma unroll
            for (int k = 0; k < 16; k++) { a0 += blo(uu[k]); a1 += bhi(uu[k]); }
        }
        for (; j + 4 <= m; j += 4) {
            u32 uu[4];
#pragma unroll
            for (int k = 0; k < 4; k++) {
                int idx = __shfl(ci, j + k);
                uu[k] = *(const u32*)(gl + (size_t)idx * HID);
            }
#pragma unroll
            for (int k = 0; k < 4; k++) { a0 += blo(uu[k]); a1 += bhi(uu[k]); }
        }
        if (j < m) {
            int r = m - j;
            u32 uu[3];
#pragma unroll
            for (int k = 0; k < 3; k++) {
                int jk = j + k; int idx = __shfl(ci, (jk < m) ? jk : j);
                uu[k] = *(const u32*)(gl + (size_t)idx * HID);
            }
#pragma unroll
            for (int k = 0; k < 3; k++) {
                float mk = (k < r) ? 1.f : 0.f;
                a0 = fmaf(mk, blo(uu[k]), a0); a1 = fmaf(mk, bhi(uu[k]), a1);
            }
        }
        e += m;
    }

    float dv = dinv[v];
    if (LAYER == 1) {
        float o0 = fmaxf(a0 * dv + bias[f0],     0.f) * dv;
        float o1 = fmaxf(a1 * dv + bias[f0 + 1], 0.f) * dv;
        u32 pk = (u32)f2b(o0) | ((u32)f2b(o1) << 16);
        int l15 = l & 15;
        u32 w0 = __shfl(pk, l15 * 4 + 0);
        u32 w1 = __shfl(pk, l15 * 4 + 1);
        u32 w2 = __shfl(pk, l15 * 4 + 2);
        u32 w3 = __shfl(pk, l15 * 4 + 3);
        if (l < 16) {
            u32x4 vv = (u32x4){w0, w1, w2, w3};
            *(u32x4*)(tout + (size_t)v * HID + l * 8) = vv;
        }
    } else {
        int bg = batch[v];
        atomicAdd(&psum[(size_t)bg * HID + f0],     a0 * dv);
        atomicAdd(&psum[(size_t)bg * HID + f0 + 1], a1 * dv);
    }
}

// ---------------- pooled FC: out = (psum/cnt) @ Wc + bc ----------------
__global__ __launch_bounds__(64) void k_fc(const float* __restrict__ psum,
                                           const int* __restrict__ cntg,
                                           const float* __restrict__ Wc,
                                           const float* __restrict__ bc,
                                           float* __restrict__ out) {
    __shared__ float pooled[HID];
    int gph = blockIdx.x, t = threadIdx.x;
    float inv = 1.f / fmaxf((float)cntg[gph], 1.f);
    for (int k = t; k < HID; k += 64) pooled[k] = psum[gph * HID + k] * inv;
    __syncthreads();
    float acc = bc[t];
    for (int k = 0; k < HID; k++) acc += pooled[k] * Wc[k * NOUT + t];
    out[gph * NOUT + t] = acc;
}

extern "C" void kernel_launch(void* const* d_in, const int* in_sizes, int n_in,
                              void* d_out, int out_size, void* d_ws, size_t ws_size,
                              hipStream_t stream) {
    const float* x     = (const float*)d_in[0];
    const int*   ei    = (const int*)d_in[1];
    const int*   batch = (const int*)d_in[3];
    const float* W1    = (const float*)d_in[4];
    const float* b1    = (const float*)d_in[5];
    const float* W2    = (const float*)d_in[6];
    const float* b2    = (const float*)d_in[7];
    const float* Wfc   = (const float*)d_in[8];
    const float* bfc   = (const float*)d_in[9];
    float* out = (float*)d_out;

    const int* src = ei;
    const int* dst = ei + NE;

    char* p = (char*)d_ws;
    auto take = [&](size_t bytes) { char* r = p; p += (bytes + 255) & ~(size_t)255; return r; };
    // zero-group (one memset covers bcnt..psum)
    int*   bcnt = (int*)take((size_t)NBUK * 4);
    int*   cntg = (int*)take((size_t)NG * 4);
    float* psum = (float*)take((size_t)NG * HID * 4);
    size_t zspan = (size_t)((char*)psum + (size_t)NG * HID * 4 - (char*)bcnt);
    // rest
    int*   boff = (int*)take((size_t)(NBUK + 1) * 4);
    int*   gcur = (int*)take((size_t)NBUK * 4);
    int*   rp   = (int*)take((size_t)(NN + 1) * 4);
    float* dinv = (float*)take((size_t)NN * 4);
    u16*   Wp1  = (u16*)take((size_t)32 * 64 * 8 * 2);
    float* Wc   = (float*)take((size_t)HID * NOUT * 4);
    float* bc   = (float*)take((size_t)NOUT * 4);
    int*   col  = (int*)take((size_t)NE * 4);
    u16*   g    = (u16*)take((size_t)NN * HID * 2);
    u16*   t    = (u16*)take((size_t)NN * HID * 2);
    EdgeT* ebuf = (EdgeT*)g;   // aliased: ebuf consumed by k_bucketc before k_gemm writes g

    hipMemsetAsync(bcnt, 0, zspan, stream);

    k_bhist  <<<NAH, 256, 0, stream>>>(dst, bcnt);
    k_bscan  <<<1, 256, 0, stream>>>(bcnt, boff, gcur, rp);
    k_scatter<<<NSC, 256, 0, stream>>>(src, dst, gcur, ebuf);
    k_bucketc<<<NBUK, 256, 0, stream>>>(ebuf, boff, batch, rp, dinv, cntg, col);
    k_pack   <<<8, 256, 0, stream>>>(W1, Wp1);
    k_wc     <<<(HID * NOUT + 255) / 256, 256, 0, stream>>>(W2, Wfc, b2, bfc, Wc, bc);

    k_gemm   <<<(NN + 63) / 64, 256, 0, stream>>>(x, Wp1, dinv, g);
    k_agg<1> <<<(NN + 3) / 4, 256, 0, stream>>>(g, rp, col, dinv, b1, t, nullptr, nullptr);
    k_agg<2> <<<(NN + 3) / 4, 256, 0, stream>>>(t, rp, col, dinv, nullptr, nullptr, batch, psum);
    k_fc     <<<NG, 64, 0, stream>>>(psum, cntg, Wc, bc, out);
}

// Round 15
// 291.790 us; speedup vs baseline: 7.0790x; 1.1698x over previous
//
#include <hip/hip_runtime.h>
#include <stdint.h>

#define NN   100000
#define NE   1600000
#define NG   512
#define HID  128
#define NOUT 64
#define BK   512
#define NBUK ((NN + BK - 1) / BK)      // 196 buckets of 512 nodes
#define AHIST_E 4096
#define NAH  ((NE + AHIST_E - 1) / AHIST_E)   // 391
#define CHUNK 8192
#define NSC  ((NE + CHUNK - 1) / CHUNK)       // 196

typedef __bf16 bf16_t;
typedef bf16_t bf16x8 __attribute__((ext_vector_type(8)));
typedef float  f32x4  __attribute__((ext_vector_type(4)));
typedef unsigned int u32;
typedef u32 u32x2 __attribute__((ext_vector_type(2)));
typedef u32 u32x4 __attribute__((ext_vector_type(4)));
typedef unsigned short u16;

struct __align__(8) EdgeT { int d, s; };

__device__ __forceinline__ u16 f2b(float f) {
    union { float f; u32 u; } v; v.f = f;
    u32 u = v.u + 0x7fffu + ((v.u >> 16) & 1u);   // RNE
    return (u16)(u >> 16);
}
__device__ __forceinline__ float blo(u32 u) {
    union { u32 u; float f; } v; v.u = u << 16; return v.f;
}
__device__ __forceinline__ float bhi(u32 u) {
    union { u32 u; float f; } v; v.u = u & 0xffff0000u; return v.f;
}

// ---------------- CSR build, bucketed (R6-proven) ----------------
__global__ __launch_bounds__(256) void k_bhist(const int* __restrict__ dst,
                                               int* __restrict__ bcnt) {
    __shared__ int h[NBUK];
    int t = threadIdx.x;
    for (int i = t; i < NBUK; i += 256) h[i] = 0;
    __syncthreads();
    int e0 = blockIdx.x * AHIST_E;
    int e1 = min(NE, e0 + AHIST_E);
    for (int e = e0 + t; e < e1; e += 256) atomicAdd(&h[dst[e] >> 9], 1);
    __syncthreads();
    for (int i = t; i < NBUK; i += 256) if (h[i]) atomicAdd(&bcnt[i], h[i]);
}

__global__ __launch_bounds__(256) void k_bscan(const int* __restrict__ bcnt,
                                               int* __restrict__ boff, int* __restrict__ gcur,
                                               int* __restrict__ rp) {
    __shared__ int sh[256];
    int t = threadIdx.x;
    int v = (t < NBUK) ? bcnt[t] : 0;
    sh[t] = v; __syncthreads();
    for (int off = 1; off < 256; off <<= 1) {
        int x = (t >= off) ? sh[t - off] : 0;
        __syncthreads();
        sh[t] += x;
        __syncthreads();
    }
    if (t < NBUK) { int b = sh[t] - v; boff[t] = b; gcur[t] = b; }
    if (t == 0) { boff[NBUK] = NE; rp[NN] = NE; }
}

__global__ __launch_bounds__(256) void k_scatter(const int* __restrict__ src,
                                                 const int* __restrict__ dst,
                                                 int* __restrict__ gcur,
                                                 EdgeT* __restrict__ ebuf) {
    __shared__ int hist[NBUK], base[NBUK];
    int t = threadIdx.x;
    for (int i = t; i < NBUK; i += 256) hist[i] = 0;
    __syncthreads();
    int e0 = blockIdx.x * CHUNK;
    int e1 = min(NE, e0 + CHUNK);
    for (int e = e0 + t; e < e1; e += 256) atomicAdd(&hist[dst[e] >> 9], 1);
    __syncthreads();
    for (int i = t; i < NBUK; i += 256) {
        int h = hist[i];
        base[i] = h ? atomicAdd(&gcur[i], h) : 0;
        hist[i] = 0;
    }
    __syncthreads();
    for (int e = e0 + t; e < e1; e += 256) {
        int d = dst[e], bk = d >> 9;
        int r = atomicAdd(&hist[bk], 1);
        EdgeT p; p.d = d; p.s = src[e];
        ebuf[base[bk] + r] = p;
    }
}

__global__ __launch_bounds__(256) void k_bucketc(const EdgeT* __restrict__ ebuf,
                                                 const int* __restrict__ boff,
                                                 const int* __restrict__ batch,
                                                 int* __restrict__ rp, float* __restrict__ dinv,
                                                 int* __restrict__ cntg, int* __restrict__ col) {
    __shared__ int cnt[BK], pos[BK], run[BK], s2[256];
    int b = blockIdx.x, t = threadIdx.x;
    int d0 = b * BK;
    int e0 = boff[b], e1 = boff[b + 1];
    for (int i = t; i < BK; i += 256) { cnt[i] = 0; run[i] = 0; }
    __syncthreads();
    for (int e = e0 + t; e < e1; e += 256) atomicAdd(&cnt[ebuf[e].d - d0], 1);
    __syncthreads();
    for (int i = t; i < BK; i += 256) {
        int v = d0 + i;
        if (v < NN) {
            dinv[v] = rsqrtf((float)(cnt[i] + 1));
            atomicAdd(&cntg[batch[v]], 1);
        }
    }
    int c0 = cnt[2 * t], c1 = cnt[2 * t + 1];
    int s = c0 + c1; s2[t] = s; __syncthreads();
    for (int off = 1; off < 256; off <<= 1) {
        int x = (t >= off) ? s2[t - off] : 0;
        __syncthreads();
        s2[t] += x;
        __syncthreads();
    }
    int bse = s2[t] - s;
    pos[2 * t] = bse; pos[2 * t + 1] = bse + c0;
    __syncthreads();
    for (int i = t; i < BK; i += 256) {
        int v = d0 + i;
        if (v < NN) rp[v] = e0 + pos[i];
    }
    for (int e = e0 + t; e < e1; e += 256) {
        EdgeT p = ebuf[e];
        int i = p.d - d0;
        int r = atomicAdd(&run[i], 1);
        col[e0 + pos[i] + r] = p.s;
    }
}

// ---------------- fused weight prep (R11-proven) ----------------
// tid<2048: pack W1 (8 col-frags, n_global=(l&15)*8+c)
// [2048,10240): Wcp = packed bf16 of Wc=W2@Wfc (4 col-frags, n=(l&15)*4+c)
// [10240,10304): bc = b2 @ Wfc + bfc
__global__ void k_wprep(const float* __restrict__ W1, u16* __restrict__ Wp,
                        const float* __restrict__ W2, const float* __restrict__ Wfc,
                        const float* __restrict__ b2, const float* __restrict__ bfc,
                        u16* __restrict__ Wcp, float* __restrict__ bc) {
    int tid = blockIdx.x * blockDim.x + threadIdx.x;
    if (tid < 2048) {
        int f = tid >> 6, l = tid & 63;
        int c = f >> 2, s = f & 3;
        int n  = (l & 15) * 8 + c;
        int k0 = s * 32 + ((l >> 4) << 3);
#pragma unroll
        for (int j = 0; j < 8; j++) Wp[tid * 8 + j] = f2b(W1[(k0 + j) * HID + n]);
    } else if (tid < 2048 + HID * NOUT) {
        int t2 = tid - 2048;
        int k = t2 >> 6, n = t2 & 63;
        float a = 0.f;
        for (int m = 0; m < HID; m++) a += W2[k * HID + m] * Wfc[m * NOUT + n];
        int s = k >> 5, lh = (k >> 3) & 3, j = k & 7;
        int c = n & 3, l15 = n >> 2;
        int l = (lh << 4) | l15, f = c * 4 + s;
        Wcp[((f * 64 + l) << 3) + j] = f2b(a);
    } else if (tid < 2048 + HID * NOUT + NOUT) {
        int o = tid - 2048 - HID * NOUT;
        float a = bfc[o];
        for (int k = 0; k < HID; k++) a += b2[k] * Wfc[k * NOUT + o];
        bc[o] = a;
    }
}

// ---------------- GEMM1: g = bf16((X @ W1) * dinv[row]), [NN][128] ----------------
__global__ __launch_bounds__(256) void k_gemm(const float* __restrict__ Xf,
                                              const u16* __restrict__ Wp,
                                              const float* __restrict__ dinv,
                                              u16* __restrict__ Gout) {
    int w = threadIdx.x >> 6, l = threadIdx.x & 63;
    int r0  = blockIdx.x * 64 + w * 16;
    int l15 = l & 15, lh = l >> 4;
    int arow = r0 + l15;
    int arc  = (arow < NN) ? arow : (NN - 1);

    f32x4 acc[8];
#pragma unroll
    for (int c = 0; c < 8; c++) acc[c] = (f32x4){0.f, 0.f, 0.f, 0.f};

#pragma unroll
    for (int s = 0; s < 4; s++) {
        int k0 = s * 32 + lh * 8;
        f32x4 p0 = *(const f32x4*)(Xf + (size_t)arc * HID + k0);
        f32x4 p1 = *(const f32x4*)(Xf + (size_t)arc * HID + k0 + 4);
        union { bf16x8 v; u16 h[8]; } au;
#pragma unroll
        for (int j = 0; j < 4; j++) { au.h[j] = f2b(p0[j]); au.h[j + 4] = f2b(p1[j]); }
        bf16x8 a = au.v;
#pragma unroll
        for (int c = 0; c < 8; c++) {
            bf16x8 b = *(const bf16x8*)(Wp + ((c * 4 + s) * 64 + l) * 8);
            acc[c] = __builtin_amdgcn_mfma_f32_16x16x32_bf16(a, b, acc[c], 0, 0, 0);
        }
    }
#pragma unroll
    for (int q = 0; q < 4; q++) {
        int row = r0 + lh * 4 + q;
        if (row < NN) {
            float dv = dinv[row];
            union { u32x4 v; u16 h[8]; } pk;
#pragma unroll
            for (int c = 0; c < 8; c++) pk.h[c] = f2b(acc[c][q] * dv);
            *(u32x4*)(Gout + (size_t)row * HID + l15 * 8) = pk.v;
        }
    }
}

// ---------------- agg1 (R6-proven): T[v] = bf16(dinv*relu(dinv*Sum + b1)) -------
__global__ __launch_bounds__(256) void k_agg1(const u16* __restrict__ g,
                                              const int* __restrict__ rp,
                                              const int* __restrict__ col,
                                              const float* __restrict__ dinv,
                                              const float* __restrict__ bias,
                                              u16* __restrict__ tout) {
    int w = threadIdx.x >> 6, l = threadIdx.x & 63;
    int v = blockIdx.x * 4 + w;
    if (v >= NN) return;
    int f0 = 2 * l;
    const u16* gl = g + f0;   // this lane's 4B column within any row

    u32 u = *(const u32*)(gl + (size_t)v * HID);   // self loop
    float a0 = blo(u), a1 = bhi(u);

    int e = rp[v], end = rp[v + 1];
    while (e < end) {
        int m = end - e; if (m > 64) m = 64;
        int ci = col[e + ((l < m) ? l : 0)];
        int j = 0;
        for (; j + 16 <= m; j += 16) {
            u32 uu[16];
#pragma unroll
            for (int k = 0; k < 16; k++) {
                int idx = __shfl(ci, j + k);
                uu[k] = *(const u32*)(gl + (size_t)idx * HID);
            }
#pragma unroll
            for (int k = 0; k < 16; k++) { a0 += blo(uu[k]); a1 += bhi(uu[k]); }
        }
        for (; j + 4 <= m; j += 4) {
            u32 uu[4];
#pragma unroll
            for (int k = 0; k < 4; k++) {
                int idx = __shfl(ci, j + k);
                uu[k] = *(const u32*)(gl + (size_t)idx * HID);
            }
#pragma unroll
            for (int k = 0; k < 4; k++) { a0 += blo(uu[k]); a1 += bhi(uu[k]); }
        }
        if (j < m) {
            int r = m - j;
            u32 uu[3];
#pragma unroll
            for (int k = 0; k < 3; k++) {
                int jk = j + k; int idx = __shfl(ci, (jk < m) ? jk : j);
                uu[k] = *(const u32*)(gl + (size_t)idx * HID);
            }
#pragma unroll
            for (int k = 0; k < 3; k++) {
                float mk = (k < r) ? 1.f : 0.f;
                a0 = fmaf(mk, blo(uu[k]), a0); a1 = fmaf(mk, bhi(uu[k]), a1);
            }
        }
        e += m;
    }

    float dv = dinv[v];
    float o0 = fmaxf(a0 * dv + bias[f0],     0.f) * dv;
    float o1 = fmaxf(a1 * dv + bias[f0 + 1], 0.f) * dv;
    u32 pk = (u32)f2b(o0) | ((u32)f2b(o1) << 16);
    int l15 = l & 15;
    u32 w0 = __shfl(pk, l15 * 4 + 0);
    u32 w1 = __shfl(pk, l15 * 4 + 1);
    u32 w2 = __shfl(pk, l15 * 4 + 2);
    u32 w3 = __shfl(pk, l15 * 4 + 3);
    if (l < 16) {
        u32x4 vv = (u32x4){w0, w1, w2, w3};
        *(u32x4*)(tout + (size_t)v * HID + l * 8) = vv;
    }
}

// ---------------- GEMM2: U = bf16(T @ Wc), [NN][64] (128B rows) ----------------
__global__ __launch_bounds__(256) void k_gemm2(const u16* __restrict__ T,
                                               const u16* __restrict__ Wcp,
                                               u16* __restrict__ U) {
    int w = threadIdx.x >> 6, l = threadIdx.x & 63;
    int r0  = blockIdx.x * 64 + w * 16;
    int l15 = l & 15, lh = l >> 4;
    int arow = r0 + l15;
    int arc  = (arow < NN) ? arow : (NN - 1);

    f32x4 acc[4];
#pragma unroll
    for (int c = 0; c < 4; c++) acc[c] = (f32x4){0.f, 0.f, 0.f, 0.f};

#pragma unroll
    for (int s = 0; s < 4; s++) {
        int k0 = s * 32 + lh * 8;
        bf16x8 a = *(const bf16x8*)(T + (size_t)arc * HID + k0);
#pragma unroll
        for (int c = 0; c < 4; c++) {
            bf16x8 b = *(const bf16x8*)(Wcp + ((c * 4 + s) * 64 + l) * 8);
            acc[c] = __builtin_amdgcn_mfma_f32_16x16x32_bf16(a, b, acc[c], 0, 0, 0);
        }
    }
    // lane l15 owns global cols [4*l15, 4*l15+4) -> 8B store
#pragma unroll
    for (int q = 0; q < 4; q++) {
        int row = r0 + lh * 4 + q;
        if (row < NN) {
            union { u32x2 v; u16 h[4]; } pk;
#pragma unroll
            for (int c = 0; c < 4; c++) pk.h[c] = f2b(acc[c][q]);
            *(u32x2*)(U + (size_t)row * NOUT + l15 * 4) = pk.v;
        }
    }
}

// ---------------- agg2u: R6-shape walk over U, one u16 per lane ----------------
// Identical loop structure/depth to agg1 (16 unmasked loads in flight), but each
// load is 64 lanes x 2B = one full 128B U-row -> HALF the cache lines per edge.
// Lane owns feature l; one atomicAdd per lane at the end.
__global__ __launch_bounds__(256) void k_agg2u(const u16* __restrict__ U,
                                               const int* __restrict__ rp,
                                               const int* __restrict__ col,
                                               const float* __restrict__ dinv,
                                               const int* __restrict__ batch,
                                               float* __restrict__ psum) {
    int w = threadIdx.x >> 6, l = threadIdx.x & 63;
    int v = blockIdx.x * 4 + w;
    if (v >= NN) return;
    const u16* Ul = U + l;    // this lane's 2B column within any 128B row

    float a0 = blo((u32)Ul[(size_t)v * NOUT]);     // self loop

    int e = rp[v], end = rp[v + 1];
    while (e < end) {
        int m = end - e; if (m > 64) m = 64;
        int ci = col[e + ((l < m) ? l : 0)];
        int j = 0;
        for (; j + 16 <= m; j += 16) {
            u16 uu[16];
#pragma unroll
            for (int k = 0; k < 16; k++) {
                int idx = __shfl(ci, j + k);
                uu[k] = Ul[(size_t)idx * NOUT];
            }
#pragma unroll
            for (int k = 0; k < 16; k++) a0 += blo((u32)uu[k]);
        }
        for (; j + 4 <= m; j += 4) {
            u16 uu[4];
#pragma unroll
            for (int k = 0; k < 4; k++) {
                int idx = __shfl(ci, j + k);
                uu[k] = Ul[(size_t)idx * NOUT];
            }
#pragma unroll
            for (int k = 0; k < 4; k++) a0 += blo((u32)uu[k]);
        }
        if (j < m) {
            int r = m - j;
            u16 uu[3];
#pragma unroll
            for (int k = 0; k < 3; k++) {
                int jk = j + k; int idx = __shfl(ci, (jk < m) ? jk : j);
                uu[k] = Ul[(size_t)idx * NOUT];
            }
#pragma unroll
            for (int k = 0; k < 3; k++) {
                float mk = (k < r) ? 1.f : 0.f;
                a0 = fmaf(mk, blo((u32)uu[k]), a0);
            }
        }
        e += m;
    }

    atomicAdd(&psum[(size_t)batch[v] * NOUT + l], a0 * dinv[v]);
}

// ---------------- final: out[g][o] = psum[g][o]/cnt + bc[o] ----------------
__global__ __launch_bounds__(256) void k_fc(const float* __restrict__ psum,
                                            const int* __restrict__ cntg,
                                            const float* __restrict__ bc,
                                            float* __restrict__ out) {
    int tid = blockIdx.x * blockDim.x + threadIdx.x;
    if (tid < NG * NOUT) {
        int gph = tid >> 6, o = tid & 63;
        float inv = 1.f / fmaxf((float)cntg[gph], 1.f);
        out[tid] = psum[tid] * inv + bc[o];
    }
}

extern "C" void kernel_launch(void* const* d_in, const int* in_sizes, int n_in,
                              void* d_out, int out_size, void* d_ws, size_t ws_size,
                              hipStream_t stream) {
    const float* x     = (const float*)d_in[0];
    const int*   ei    = (const int*)d_in[1];
    const int*   batch = (const int*)d_in[3];
    const float* W1    = (const float*)d_in[4];
    const float* b1    = (const float*)d_in[5];
    const float* W2    = (const float*)d_in[6];
    const float* b2    = (const float*)d_in[7];
    const float* Wfc   = (const float*)d_in[8];
    const float* bfc   = (const float*)d_in[9];
    float* out = (float*)d_out;

    const int* src = ei;
    const int* dst = ei + NE;

    char* p = (char*)d_ws;
    auto take = [&](size_t bytes) { char* r = p; p += (bytes + 255) & ~(size_t)255; return r; };
    // zero-group (one memset covers bcnt..psum)
    int*   bcnt = (int*)take((size_t)NBUK * 4);
    int*   cntg = (int*)take((size_t)NG * 4);
    float* psum = (float*)take((size_t)NG * NOUT * 4);
    size_t zspan = (size_t)((char*)psum + (size_t)NG * NOUT * 4 - (char*)bcnt);
    int*   boff = (int*)take((size_t)(NBUK + 1) * 4);
    int*   gcur = (int*)take((size_t)NBUK * 4);
    int*   rp   = (int*)take((size_t)(NN + 1) * 4);
    float* dinv = (float*)take((size_t)NN * 4);
    u16*   Wp1  = (u16*)take((size_t)32 * 64 * 8 * 2);
    u16*   Wcp  = (u16*)take((size_t)16 * 64 * 8 * 2);
    float* bc   = (float*)take((size_t)NOUT * 4);
    int*   col  = (int*)take((size_t)NE * 4);
    u16*   g    = (u16*)take((size_t)NN * HID * 2);
    u16*   t    = (u16*)take((size_t)NN * HID * 2);
    u16*   U    = (u16*)take((size_t)NN * NOUT * 2);
    EdgeT* ebuf = (EdgeT*)g;   // aliased: ebuf consumed by k_bucketc before k_gemm writes g

    hipMemsetAsync(bcnt, 0, zspan, stream);

    k_bhist  <<<NAH, 256, 0, stream>>>(dst, bcnt);
    k_bscan  <<<1, 256, 0, stream>>>(bcnt, boff, gcur, rp);
    k_scatter<<<NSC, 256, 0, stream>>>(src, dst, gcur, ebuf);
    k_bucketc<<<NBUK, 256, 0, stream>>>(ebuf, boff, batch, rp, dinv, cntg, col);
    k_wprep  <<<(2048 + HID * NOUT + NOUT + 255) / 256, 256, 0, stream>>>
             (W1, Wp1, W2, Wfc, b2, bfc, Wcp, bc);

    k_gemm   <<<(NN + 63) / 64, 256, 0, stream>>>(x, Wp1, dinv, g);
    k_agg1   <<<(NN + 3) / 4, 256, 0, stream>>>(g, rp, col, dinv, b1, t);
    k_gemm2  <<<(NN + 63) / 64, 256, 0, stream>>>(t, Wcp, U);
    k_agg2u  <<<(NN + 3) / 4, 256, 0, stream>>>(U, rp, col, dinv, batch, psum);
    k_fc     <<<(NG * NOUT + 255) / 256, 256, 0, stream>>>(psum, cntg, bc, out);
}